// Round 8
// baseline (124.906 us; speedup 1.0000x reference)
//
#include <hip/hip_runtime.h>

#define HH 260
#define WW 346
#define CC 1212            // real channel count (pred layout)
#define CP 1280            // padded compact space: [0,640) pol0, [640,1280) pol1
#define HALF 640
#define NA 606             // active channels per polarity (260 + 346)
#define BB 16
#define TT 4096
#define INV_TEMP (1.0f/256.0f)
#define KCH 256            // chunks per batch
#define LCH 16             // TT / KCH
#define NG 16              // groups per batch
#define GSZ 16             // chunks per group
#define GLEN (GSZ * LCH)   // 256
#define NJ 10              // compact registers per polarity set (640/64)

// ---------------- Phase 1: per-chunk local state (zero carry), 4 chunks/block ----------------
__global__ __launch_bounds__(256) void p1_local(const float* __restrict__ target,
                                                float* __restrict__ Lbuf) {
    const int blk = blockIdx.x;            // BB*KCH/4
    const int b = blk >> 6;
    const int k0 = (blk & 63) << 2;
    const int tid = threadIdx.x;
    const int w = tid >> 6, lane = tid & 63;
    const int k = k0 + w;
    const int a = k * LCH;

    __shared__ float tg[4][LCH][4];
    __shared__ float tnextS[4];
    tg[tid >> 6][(tid >> 2) & 15][tid & 3] =
        target[((size_t)b * TT + k0 * LCH) * 4 + tid];
    if (tid < 4) {
        const int kk = k0 + tid;
        tnextS[tid] = (kk < KCH - 1) ? target[((size_t)b * TT + (kk + 1) * LCH) * 4] : 0.0f;
    }
    __syncthreads();

    float s0[NJ], s1[NJ];
#pragma unroll
    for (int j = 0; j < NJ; ++j) { s0[j] = 0.f; s1[j] = 0.f; }

    for (int li = LCH - 1; li >= 0; --li) {
        const int i = a + li;
        const float ti = tg[w][li][0];
        const float tn = (li == LCH - 1) ? tnextS[w] : tg[w][li + 1][0];
        const float d = (i >= TT - 1) ? 0.0f : __expf(-(tn - ti) * INV_TEMP);
        const int y = (int)tg[w][li][1], x = (int)tg[w][li][2], p = (int)tg[w][li][3];
        const int uy = y, ux = 260 + x;
        if (p == 0) {
#pragma unroll
            for (int j = 0; j < NJ; ++j) {
                const int u = lane + 64 * j;
                const float add = (u == uy ? 1.f : 0.f) + (u == ux ? 1.f : 0.f);
                s0[j] = fmaf(s0[j], d, add);
                s1[j] *= d;
            }
        } else {
#pragma unroll
            for (int j = 0; j < NJ; ++j) {
                const int u = lane + 64 * j;
                const float add = (u == uy ? 1.f : 0.f) + (u == ux ? 1.f : 0.f);
                s1[j] = fmaf(s1[j], d, add);
                s0[j] *= d;
            }
        }
    }
    float* __restrict__ out = Lbuf + (size_t)(b * KCH + k) * CP;
#pragma unroll
    for (int j = 0; j < NJ; ++j) {
        out[lane + 64 * j] = s0[j];
        out[HALF + lane + 64 * j] = s1[j];
    }
}

// ------- Phase 2a: within-group (16 chunks) suffix combine -------
__global__ __launch_bounds__(256) void p2a(const float* __restrict__ target,
                                           const float* __restrict__ Lbuf,
                                           float* __restrict__ LCin,
                                           float* __restrict__ GroupL) {
    const int blk = blockIdx.x;            // BB*NG*5
    const int ct = blk % 5;
    const int bg = blk / 5;                // b*NG + g
    const int b = bg >> 4, g = bg & 15;
    const int c = ct * 256 + threadIdx.x;  // < CP

    float carry = 0.f;
#pragma unroll
    for (int kk = GSZ - 1; kk >= 0; --kk) {
        const int k = g * GSZ + kk;
        const size_t idx = ((size_t)(b * KCH + k)) * CP + c;
        LCin[idx] = carry;
        float P = 0.f;
        if (k < KCH - 1) {
            const float ta = target[((size_t)b * TT + k * LCH) * 4];
            const float te = target[((size_t)b * TT + (k + 1) * LCH) * 4];
            P = __expf(-(te - ta) * INV_TEMP);
        }
        carry = fmaf(P, carry, Lbuf[idx]);
    }
    GroupL[(size_t)bg * CP + c] = carry;
}

// ------- Phase 2b: super-scan across 16 groups (preloaded) -------
__global__ __launch_bounds__(256) void p2b(const float* __restrict__ target,
                                           const float* __restrict__ GroupL,
                                           float* __restrict__ SC) {
    const int blk = blockIdx.x;            // BB*5
    const int ct = blk % 5;
    const int b = blk / 5;
    const int c = ct * 256 + threadIdx.x;

    float Gv[NG], GP[NG];
#pragma unroll
    for (int g = 0; g < NG; ++g)
        Gv[g] = GroupL[((size_t)(b * NG + g)) * CP + c];
#pragma unroll
    for (int g = 0; g < NG; ++g) {
        if (g < NG - 1) {
            const float ta = target[((size_t)b * TT + g * GLEN) * 4];
            const float te = target[((size_t)b * TT + (g + 1) * GLEN) * 4];
            GP[g] = __expf(-(te - ta) * INV_TEMP);
        } else GP[g] = 0.f;
    }
    float carry = 0.f;
#pragma unroll
    for (int g = NG - 1; g >= 0; --g) {
        SC[((size_t)(b * NG + g)) * CP + c] = carry;
        carry = fmaf(GP[g], carry, Gv[g]);
    }
}

// ------- Phase 3: replay + fused loss, SEGMENT-SPLIT (y-waves / x-waves) -------
// loss(b,t) = [log zpy - dty/zsy] + [log zpx - dtx/zsx] separates; each wave
// handles one chunk x one segment: half the state, half the step cost, 2x waves.
template <int SEG>
__device__ __forceinline__ void p3_seg(const float* __restrict__ pred,
                                       const float* __restrict__ target,
                                       const float* __restrict__ LCin,
                                       const float* __restrict__ SC,
                                       double* __restrict__ partials,
                                       int blk) {
    constexpr int NR = (SEG == 0) ? 5 : 6;       // regs per plane
    constexpr int SEGLEN = (SEG == 0) ? HH : WW; // 260 / 346
    constexpr int SOFF = (SEG == 0) ? 0 : 260;   // offset within compact plane

    const int b = blk >> 6;
    const int k0 = (blk & 63) << 2;
    const int tid = threadIdx.x;
    const int w = tid >> 6, lane = tid & 63;
    const int k = k0 + w;
    const int g = k >> 4;
    const int a = k * LCH;

    __shared__ float tg[4][LCH][4];
    __shared__ float tnextS[4];
    tg[tid >> 6][(tid >> 2) & 15][tid & 3] =
        target[((size_t)b * TT + k0 * LCH) * 4 + tid];
    if (tid < 4) {
        const int kk = k0 + tid;
        tnextS[tid] = (kk < KCH - 1) ? target[((size_t)b * TT + (kk + 1) * LCH) * 4] : 0.0f;
    }
    __syncthreads();

    float Qk = 0.f;
    if (g < NG - 1) {
        const float tge = target[((size_t)b * TT + (g + 1) * GLEN) * 4];
        const float tk1 = target[((size_t)b * TT + (k + 1) * LCH) * 4];
        Qk = __expf(-(tge - tk1) * INV_TEMP);
    }

    const float* __restrict__ lc = LCin + (size_t)(b * KCH + k) * CP + SOFF;
    const float* __restrict__ sc = SC + ((size_t)(b * NG + g)) * CP + SOFF;
    float sA[2][NR];
#pragma unroll
    for (int pl = 0; pl < 2; ++pl)
#pragma unroll
        for (int j = 0; j < NR; ++j) {
            const int u = lane + 64 * j;
            const int uc = (u < SEGLEN) ? u : (SEGLEN - 1);    // clamp (pad masked at use)
            const float v = fmaf(Qk, sc[pl * HALF + uc], lc[pl * HALF + uc]);
            sA[pl][j] = (u < SEGLEN) ? v : 0.f;
        }

    auto loadRow = [&](float (&pr)[NR], int li) {
        const int pn = (int)tg[w][li][3];
        const float* __restrict__ prow = pred + ((size_t)b * TT + a + li) * CC
                                       + (SEG == 0 ? pn * HH : 2 * HH + pn * WW);
#pragma unroll
        for (int j = 0; j < NR; ++j) {
            const int u = lane + 64 * j;
            pr[j] = prow[(u < SEGLEN) ? u : (SEGLEN - 1)];     // clamped; masked at use
        }
    };

    double lacc = 0.0;

    auto step = [&](int li, float (&pr)[NR]) {
        const int i = a + li;
        const float ti = tg[w][li][0];
        const float tn = (li == LCH - 1) ? tnextS[w] : tg[w][li + 1][0];
        const float d = (i == 0 || i >= TT - 1) ? 0.0f : __expf(-(tn - ti) * INV_TEMP);
        const int ev = (int)tg[w][li][SEG == 0 ? 1 : 2];       // event channel in this seg
        const int p = (int)tg[w][li][3];

        float zp = 0.f, zs = 0.f, dt = 0.f;

        auto inner = [&](float (&SA)[NR], float (&SO)[NR]) {
#pragma unroll
            for (int j = 0; j < NR; ++j) {
                const int u = lane + 64 * j;
                const float add = (u == ev) ? 1.f : 0.f;
                SA[j] = fmaf(SA[j], d, add);
                SO[j] *= d;
                const float prv = pr[j];
                float es = __expf(SA[j]);
                float ep = __expf(prv);
                if (j == NR - 1) {                             // mask pad lanes
                    const float m = (u < SEGLEN) ? 1.f : 0.f;
                    es *= m; ep *= m;
                }
                zp += ep; zs += es; dt = fmaf(es, prv, dt);
            }
        };
        if (p == 0) inner(sA[0], sA[1]); else inner(sA[1], sA[0]);

#pragma unroll
        for (int off = 32; off > 0; off >>= 1) {
            zp += __shfl_xor(zp, off);
            zs += __shfl_xor(zs, off);
            dt += __shfl_xor(dt, off);
        }
        lacc += (double)(__logf(zp) - __fdividef(dt, zs));
    };

    float prA[NR], prB[NR];
    loadRow(prA, LCH - 1);
    for (int li = LCH - 1; li >= 1; --li) {
        loadRow(prB, li - 1);          // next row's loads in flight during step
        step(li, prA);
#pragma unroll
        for (int j = 0; j < NR; ++j) prA[j] = prB[j];
    }
    step(0, prA);

    if (lane == 0) partials[SEG * (BB * KCH) + b * KCH + k] = lacc;
}

__global__ __launch_bounds__(256, 8) void p3_loss(const float* __restrict__ pred,
                                                  const float* __restrict__ target,
                                                  const float* __restrict__ LCin,
                                                  const float* __restrict__ SC,
                                                  double* __restrict__ partials) {
    if (blockIdx.y == 0) p3_seg<0>(pred, target, LCin, SC, partials, blockIdx.x);
    else                 p3_seg<1>(pred, target, LCin, SC, partials, blockIdx.x);
}

// ---------------- Finalize: sum 2*B*KCH partials ----------------
__global__ void p4_final(const double* __restrict__ partials, float* __restrict__ out) {
    const int tid = threadIdx.x;   // 256
    double sum = 0.0;
    for (int i = tid; i < 2 * BB * KCH; i += 256) sum += partials[i];
#pragma unroll
    for (int off = 32; off > 0; off >>= 1) sum += __shfl_xor(sum, off);
    __shared__ double sred[4];
    if ((tid & 63) == 0) sred[tid >> 6] = sum;
    __syncthreads();
    if (tid == 0)
        out[0] = (float)((sred[0] + sred[1] + sred[2] + sred[3]) / (double)((size_t)BB * TT));
}

extern "C" void kernel_launch(void* const* d_in, const int* in_sizes, int n_in,
                              void* d_out, int out_size, void* d_ws, size_t ws_size,
                              hipStream_t stream) {
    const float* pred   = (const float*)d_in[0];
    const float* target = (const float*)d_in[1];
    float* out = (float*)d_out;

    // ws layout: [partials 8192 doubles = 64KB][Lbuf][LCin][GroupL][SC]
    double* partials = (double*)d_ws;
    float* Lbuf   = (float*)((char*)d_ws + 65536);
    float* LCin   = Lbuf + (size_t)BB * KCH * CP;
    float* GroupL = LCin + (size_t)BB * KCH * CP;
    float* SC     = GroupL + (size_t)BB * NG * CP;

    p1_local<<<BB * KCH / 4, 256, 0, stream>>>(target, Lbuf);
    p2a<<<BB * NG * 5, 256, 0, stream>>>(target, Lbuf, LCin, GroupL);
    p2b<<<BB * 5, 256, 0, stream>>>(target, GroupL, SC);
    dim3 g3(BB * KCH / 4, 2);
    p3_loss<<<g3, 256, 0, stream>>>(pred, target, LCin, SC, partials);
    p4_final<<<1, 256, 0, stream>>>(partials, out);
}